// Round 2
// baseline (408.987 us; speedup 1.0000x reference)
//
#include <hip/hip_runtime.h>

typedef unsigned short u16;
typedef unsigned long long u64;
typedef __attribute__((ext_vector_type(8))) short short8;
typedef __attribute__((ext_vector_type(4))) float f32x4;
typedef __attribute__((ext_vector_type(16))) float f32x16;

#define NN   4096
#define EE   131072
#define ETOT (EE + NN)
#define HH   4
#define IND  3000
#define KP   3072
#define KSP  4
#define KPER 768
#define D1   512
#define C1   128
#define C2   16

__device__ __forceinline__ float b2f(u16 u){
  union { unsigned int i; float f; } v; v.i = ((unsigned int)u) << 16; return v.f;
}
__device__ __forceinline__ u16 f2b(float f){
  unsigned int x = __float_as_uint(f);
  unsigned int r = (x + 0x7fffu + ((x >> 16) & 1u)) >> 16;
  return (u16)r;
}
__device__ __forceinline__ float lrelu(float x){ return x > 0.f ? x : 0.2f * x; }

__device__ __forceinline__ void glds16(const void* g, void* l){
  __builtin_amdgcn_global_load_lds(
      (const __attribute__((address_space(1))) unsigned int*)g,
      (__attribute__((address_space(3))) unsigned int*)l, 16, 0, 0);
}

__global__ void zero_out_kernel(float* p, int n){
  int i = blockIdx.x * blockDim.x + threadIdx.x;
  if (i < n) p[i] = 0.f;
}

// ---------------------------------------------------------------------------
// W1 fp32 [3000][512] -> transposed split Whi/Wlo [512][3072] (zeros k>=3000)
// ---------------------------------------------------------------------------
__global__ __launch_bounds__(256) void cvtW1_kernel(const float* __restrict__ W,
    u16* __restrict__ Whi, u16* __restrict__ Wlo){
  __shared__ float T[64][65];
  int wb = blockIdx.x;
  int kb = wb % 48, nbb = wb / 48;
  int k0 = kb * 64, n0 = nbb * 64;
  int t = threadIdx.x;
  #pragma unroll
  for (int rr = 0; rr < 4; ++rr){
    int kl = (t >> 4) + rr * 16;
    int nn2 = (t & 15) * 4;
    int k = k0 + kl;
    float4 v = make_float4(0.f, 0.f, 0.f, 0.f);
    if (k < IND) v = *(const float4*)(W + (size_t)k * D1 + n0 + nn2);
    T[kl][nn2] = v.x; T[kl][nn2+1] = v.y; T[kl][nn2+2] = v.z; T[kl][nn2+3] = v.w;
  }
  __syncthreads();
  int nloc = t >> 2, kseg = (t & 3) * 16;
  int n = n0 + nloc;
  #pragma unroll
  for (int c2 = 0; c2 < 2; ++c2){
    int kloc = kseg + c2 * 8;
    u16 h8[8], l8[8];
    #pragma unroll
    for (int j = 0; j < 8; ++j){
      float f = T[kloc + j][nloc];
      h8[j] = f2b(f); l8[j] = f2b(f - b2f(h8[j]));
    }
    *(uint4*)(Whi + (size_t)n * KP + k0 + kloc) = *(uint4*)h8;
    *(uint4*)(Wlo + (size_t)n * KP + k0 + kloc) = *(uint4*)l8;
  }
}

// ---------------------------------------------------------------------------
// WM/WS [512,64] fp32 -> transposed+split Wh/Wl [128 n][512 k] bf16 hi/lo
// ---------------------------------------------------------------------------
__global__ __launch_bounds__(256) void cvtW2_kernel(const float* __restrict__ WM,
    const float* __restrict__ WS, u16* __restrict__ Wh, u16* __restrict__ Wl){
  __shared__ float T[64][65];
  int half = blockIdx.y;
  int k0 = blockIdx.x * 64;
  const float* W = half ? WS : WM;
  int t = threadIdx.x;
  #pragma unroll
  for (int p = 0; p < 4; ++p){
    int r = p * 16 + (t >> 4), c4 = (t & 15) * 4;
    float4 v = *(const float4*)(W + (size_t)(k0 + r) * 64 + c4);
    T[r][c4] = v.x; T[r][c4+1] = v.y; T[r][c4+2] = v.z; T[r][c4+3] = v.w;
  }
  __syncthreads();
  #pragma unroll
  for (int p = 0; p < 4; ++p){
    int n = p * 16 + (t >> 4), k4 = (t & 15) * 4;
    u16 h4[4], l4[4];
    #pragma unroll
    for (int j = 0; j < 4; ++j){
      float f = T[k4 + j][n];
      h4[j] = f2b(f); l4[j] = f2b(f - b2f(h4[j]));
    }
    size_t o = (size_t)(half * 64 + n) * 512 + k0 + k4;
    *(ushort4*)(Wh + o) = *(ushort4*)h4;
    *(ushort4*)(Wl + o) = *(ushort4*)l4;
  }
}

// ---------------------------------------------------------------------------
// h = X @ W1 : split-precision MFMA v3, 32x32x16 shape, wave-tile 64x64.
// BM=128, BN=128, BK=64, split-K=4, 4 waves (256 thr), 2 blocks/CU.
// A: fp32 loaded direct from X, hi/lo split in-kernel (truncation-based),
//    ds_write with XOR swizzle. B: glds16 from pre-split Whi/Wlo.
// LDS traffic 192 KB/step/block (was 128 KB for 1/4 the MFMA work).
// ---------------------------------------------------------------------------
__global__ __launch_bounds__(256, 2) void gemm_mfma3(const float* __restrict__ X,
    const u16* __restrict__ Whi, const u16* __restrict__ Wlo,
    float* __restrict__ HP){
  __shared__ u16 sAh[128*64], sAl[128*64], sBh[128*64], sBl[128*64]; // 16 KB each
  int t = threadIdx.x, lane = t & 63;
  int wv = __builtin_amdgcn_readfirstlane(t >> 6);
  int wr = wv >> 1, wc = wv & 1;
  // XCD-aware decode: each XCD gets 64 consecutive lids -> 4 mb x 4 kp x 4 nb
  int bid = blockIdx.x;
  int lid = (bid & 7) * 64 + (bid >> 3);
  int nb = lid & 3;
  int g  = lid >> 2;
  int kp = g & 3, mb = g >> 2;
  int bm = mb * 128, bn = nb * 128;
  int k0 = kp * KPER;

  f32x16 acc[2][2] = {};

  // A staging: thread t -> row t>>1, k-half (t&1)*32; 8 float4 loads, split,
  // 4+4 ds_write_b128 at chunk c -> c ^ (row&7)
  int arow = t >> 1, ahalf = t & 1;
  const float* gA = X + (size_t)(bm + arow) * IND + k0 + ahalf * 32;
  char* aw_h[4]; char* aw_l[4];
  #pragma unroll
  for (int j2 = 0; j2 < 4; ++j2){
    int c = ahalf * 4 + j2;
    int cs = c ^ (arow & 7);
    aw_h[j2] = (char*)sAh + arow * 128 + cs * 16;
    aw_l[j2] = (char*)sAl + arow * 128 + cs * 16;
  }
  // B staging: 1024 slots per buffer, 4 glds16/thread/buffer
  const char* gB[8]; char* lB[8];
  #pragma unroll
  for (int q = 0; q < 8; ++q){
    int s = (q & 3) * 256 + t;
    int br = s >> 3, bc = (s & 7) ^ (br & 7);
    const u16* base = (q < 4) ? Whi : Wlo;
    gB[q] = (const char*)(base + (size_t)(bn + br) * KP + k0) + bc * 16;
    lB[q] = (char*)((q < 4) ? sBh : sBl) + s * 16;
  }
  // fragment read offsets: row = tile_row + (lane&31), chunk = 2*ks + (lane>>5)
  int l31 = lane & 31, lhi = lane >> 5;
  int aoff[2][4], boff[2][4];
  #pragma unroll
  for (int m = 0; m < 2; ++m)
    #pragma unroll
    for (int ks = 0; ks < 4; ++ks){
      int row = wr * 64 + m * 32 + l31;
      int cb = 2 * ks + lhi;
      aoff[m][ks] = row * 128 + ((cb ^ (row & 7)) * 16);
    }
  #pragma unroll
  for (int n = 0; n < 2; ++n)
    #pragma unroll
    for (int ks = 0; ks < 4; ++ks){
      int row = wc * 64 + n * 32 + l31;
      int cb = 2 * ks + lhi;
      boff[n][ks] = row * 128 + ((cb ^ (row & 7)) * 16);
    }

  for (int kb = 0; kb < KPER; kb += 64){
    // ---- A: global fp32 -> split bf16 -> LDS
    int kbase = k0 + kb + ahalf * 32;
    float4 va[8];
    const float* gk = gA + kb;
    #pragma unroll
    for (int j = 0; j < 8; ++j){
      va[j] = (kbase + j * 4 < IND) ? *(const float4*)(gk + j * 4)
                                    : make_float4(0.f, 0.f, 0.f, 0.f);
    }
    #pragma unroll
    for (int j2 = 0; j2 < 4; ++j2){
      float e[8] = { va[2*j2].x, va[2*j2].y, va[2*j2].z, va[2*j2].w,
                     va[2*j2+1].x, va[2*j2+1].y, va[2*j2+1].z, va[2*j2+1].w };
      unsigned hh8[4], ll8[4];
      #pragma unroll
      for (int p = 0; p < 4; ++p){
        unsigned x0 = __float_as_uint(e[2*p]);
        unsigned x1 = __float_as_uint(e[2*p+1]);
        hh8[p] = (x0 >> 16) | (x1 & 0xffff0000u);
        float l0 = e[2*p]   - __uint_as_float(x0 & 0xffff0000u);
        float l1 = e[2*p+1] - __uint_as_float(x1 & 0xffff0000u);
        ll8[p] = (__float_as_uint(l0) >> 16) | (__float_as_uint(l1) & 0xffff0000u);
      }
      *(uint4*)aw_h[j2] = *(uint4*)hh8;
      *(uint4*)aw_l[j2] = *(uint4*)ll8;
    }
    // ---- B: async global->LDS
    #pragma unroll
    for (int q = 0; q < 8; ++q) glds16(gB[q] + kb * 2, lB[q]);
    __syncthreads();
    // ---- MFMA: 4 k-slices x 12 MFMAs
    #pragma unroll
    for (int ks = 0; ks < 4; ++ks){
      short8 ah[2], al[2], bh[2], bl[2];
      #pragma unroll
      for (int m = 0; m < 2; ++m){
        ah[m] = *(const short8*)((const char*)sAh + aoff[m][ks]);
        al[m] = *(const short8*)((const char*)sAl + aoff[m][ks]);
      }
      #pragma unroll
      for (int n = 0; n < 2; ++n){
        bh[n] = *(const short8*)((const char*)sBh + boff[n][ks]);
        bl[n] = *(const short8*)((const char*)sBl + boff[n][ks]);
      }
      #pragma unroll
      for (int m = 0; m < 2; ++m)
        #pragma unroll
        for (int n = 0; n < 2; ++n){
          acc[m][n] = __builtin_amdgcn_mfma_f32_32x32x16_bf16(ah[m], bh[n], acc[m][n], 0, 0, 0);
          acc[m][n] = __builtin_amdgcn_mfma_f32_32x32x16_bf16(ah[m], bl[n], acc[m][n], 0, 0, 0);
          acc[m][n] = __builtin_amdgcn_mfma_f32_32x32x16_bf16(al[m], bh[n], acc[m][n], 0, 0, 0);
        }
    }
    __syncthreads();
  }
  // epilogue: C/D col = lane&31, row = (reg&3) + 8*(reg>>2) + 4*(lane>>5)
  float* hp = HP + (size_t)kp * ((size_t)NN * D1);
  #pragma unroll
  for (int m = 0; m < 2; ++m)
    #pragma unroll
    for (int n = 0; n < 2; ++n){
      int row0 = bm + wr * 64 + m * 32 + 4 * lhi;
      int col  = bn + wc * 64 + n * 32 + l31;
      #pragma unroll
      for (int r = 0; r < 16; ++r){
        int row = row0 + (r & 3) + 8 * (r >> 2);
        hp[(size_t)row * D1 + col] = acc[m][n][r];
      }
    }
}

// ---------------------------------------------------------------------------
// split-K reduce + transpose + bf16 copy + layer-1 logits, all fused.
// grid (64, 4): 64 row-tiles x 4 heads (128 cols each).
// ---------------------------------------------------------------------------
__global__ __launch_bounds__(256) void transpose_h_red(const float* __restrict__ HP,
    float* __restrict__ hT, u16* __restrict__ h16,
    const float* __restrict__ A1S, const float* __restrict__ A1D,
    float* __restrict__ es, float* __restrict__ ed){
  __shared__ float T[64][129];
  __shared__ float R1[64][4], R2[64][4];
  int bm = blockIdx.x * 64;
  int hh = blockIdx.y;
  int bc = hh * 128;
  int t = threadIdx.x;
  int r = t >> 2, c0 = (t & 3) * 32;
  const size_t NND1 = (size_t)NN * D1;
  float s1 = 0.f, s2 = 0.f;
  #pragma unroll
  for (int j = 0; j < 8; ++j){
    int c = c0 + j * 4;
    size_t off = (size_t)(bm + r) * D1 + bc + c;
    float4 v = *(const float4*)(HP + off);
    #pragma unroll
    for (int p = 1; p < 4; ++p){
      float4 u = *(const float4*)(HP + (size_t)p * NND1 + off);
      v.x += u.x; v.y += u.y; v.z += u.z; v.w += u.w;
    }
    T[r][c] = v.x; T[r][c+1] = v.y; T[r][c+2] = v.z; T[r][c+3] = v.w;
    u16 q4[4] = { f2b(v.x), f2b(v.y), f2b(v.z), f2b(v.w) };
    *(ushort4*)(h16 + off) = *(ushort4*)q4;
    int cb = bc + c;
    s1 = fmaf(v.x, A1S[cb], fmaf(v.y, A1S[cb+1], fmaf(v.z, A1S[cb+2], fmaf(v.w, A1S[cb+3], s1))));
    s2 = fmaf(v.x, A1D[cb], fmaf(v.y, A1D[cb+1], fmaf(v.z, A1D[cb+2], fmaf(v.w, A1D[cb+3], s2))));
  }
  R1[r][t & 3] = s1; R2[r][t & 3] = s2;
  __syncthreads();
  if (t < 64){
    float v1 = R1[t][0] + R1[t][1] + R1[t][2] + R1[t][3];
    float v2 = R2[t][0] + R2[t][1] + R2[t][2] + R2[t][3];
    es[(bm + t) * HH + hh] = v1;
    ed[(bm + t) * HH + hh] = v2;
  }
  int c = t >> 1, m0 = (t & 1) * 32;
  #pragma unroll
  for (int j = 0; j < 8; ++j){
    int m4 = m0 + j * 4;
    float4 o = make_float4(T[m4][c], T[m4+1][c], T[m4+2][c], T[m4+3][c]);
    *(float4*)(hT + (size_t)(bc + c) * NN + bm + m4) = o;
  }
}

// ---------------------------------------------------------------------------
// CSR build
// ---------------------------------------------------------------------------
__global__ void zero_kernel(int* p, int n){
  int i = blockIdx.x * blockDim.x + threadIdx.x;
  if (i < n) p[i] = 0;
}
__global__ void hist_kernel(const int* __restrict__ dstA, int* __restrict__ deg){
  int e = blockIdx.x * blockDim.x + threadIdx.x;
  if (e < ETOT){
    int d = (e < EE) ? dstA[e] : (e - EE);
    atomicAdd(&deg[d & (NN-1)], 1);
  }
}
__global__ __launch_bounds__(1024) void scan_kernel(const int* __restrict__ deg,
    int* __restrict__ off, int* __restrict__ cur){
  __shared__ int wsum[16];
  int t = threadIdx.x, lane = t & 63, wv = t >> 6;
  int v0 = deg[t*4], v1 = deg[t*4+1], v2 = deg[t*4+2], v3 = deg[t*4+3];
  int s = v0 + v1 + v2 + v3;
  int sc = s;
  #pragma unroll
  for (int o = 1; o < 64; o <<= 1){
    int y = __shfl_up(sc, o);
    if (lane >= o) sc += y;
  }
  if (lane == 63) wsum[wv] = sc;
  __syncthreads();
  int base = 0;
  #pragma unroll
  for (int i = 0; i < 16; ++i) base += (i < wv) ? wsum[i] : 0;
  int excl = base + sc - s;
  int a0 = excl, a1 = a0 + v0, a2 = a1 + v1, a3 = a2 + v2;
  off[t*4] = a0; off[t*4+1] = a1; off[t*4+2] = a2; off[t*4+3] = a3;
  cur[t*4] = a0; cur[t*4+1] = a1; cur[t*4+2] = a2; cur[t*4+3] = a3;
  if (t == 1023) off[4096] = base + sc;
}
__global__ void scatter_kernel(const int* __restrict__ srcA, const int* __restrict__ dstA,
    int* __restrict__ cur, int* __restrict__ sidx){
  int e = blockIdx.x * blockDim.x + threadIdx.x;
  if (e < ETOT){
    int s, d;
    if (e < EE){ s = srcA[e]; d = dstA[e]; } else { s = d = e - EE; }
    int pos = atomicAdd(&cur[d & (NN-1)], 1);
    pos = min(max(pos, 0), ETOT - 1);
    sidx[pos] = s & (NN-1);
  }
}

// ---------------------------------------------------------------------------
// sparse layer 1: single pass, unnormalized accumulate, bf16 h gather.
// Output written DIRECTLY as split bf16 hi/lo (feeds MFMA small GEMM).
// ---------------------------------------------------------------------------
__global__ __launch_bounds__(256) void sparse1(const u16* __restrict__ h16,
    const float* __restrict__ es, const float* __restrict__ ed,
    const int* __restrict__ off, const int* __restrict__ sidx,
    const float* __restrict__ bias, u16* __restrict__ x1h, u16* __restrict__ x1l){
  int n = blockIdx.x, t = threadIdx.x, w = t >> 6;
  int o0 = off[n], deg = off[n+1] - o0;
  deg = min(max(deg, 0), ETOT);
  float edn = ed[n * HH + w];
  float dsum = 1e-16f, a0 = 0.f, a1 = 0.f;
  for (int e = 0; e < deg; ++e){
    int s = sidx[o0 + e] & (NN-1);
    float we = __expf(lrelu(es[s*HH + w] + edn));
    unsigned pk = *(const unsigned*)(h16 + ((size_t)s << 9) + 2*t);
    a0 = fmaf(we, b2f((u16)(pk & 0xffff)), a0);
    a1 = fmaf(we, b2f((u16)(pk >> 16)), a1);
    dsum += we;
  }
  float inv = 1.0f / dsum;
  float v0 = a0 * inv + bias[2*t];
  float v1 = a1 * inv + bias[2*t + 1];
  u16 h0 = f2b(v0), h1 = f2b(v1);
  u16 l0 = f2b(v0 - b2f(h0)), l1 = f2b(v1 - b2f(h1));
  size_t o = ((size_t)n << 9) + 2*t;
  *(unsigned*)(x1h + o) = (unsigned)h0 | ((unsigned)h1 << 16);
  *(unsigned*)(x1l + o) = (unsigned)l0 | ((unsigned)l1 << 16);
}

// ---------------------------------------------------------------------------
// sparse layer 2: one wave per (node, branch); fp32 gather (direct output)
// ---------------------------------------------------------------------------
struct Sp2 { const float* h[2]; const float* es[2]; const float* ed[2];
             const float* bias[2]; float* out[2]; };
__global__ __launch_bounds__(64) void sparse2(Sp2 a,
    const int* __restrict__ off, const int* __restrict__ sidx){
  int n = blockIdx.x, sel = blockIdx.y;
  int lane = threadIdx.x, hh = lane >> 4;
  const float* hsrc = a.h[sel];
  const float* es = a.es[sel];
  const float* ed = a.ed[sel];
  int o0 = off[n], deg = off[n+1] - o0;
  deg = min(max(deg, 0), ETOT);
  float edn = ed[n * HH + hh];
  float dsum = 1e-16f, acc = 0.f;
  for (int e = 0; e < deg; ++e){
    int s = sidx[o0 + e] & (NN-1);
    float we = __expf(lrelu(es[s*HH + hh] + edn));
    acc = fmaf(we, hsrc[(size_t)s * 64 + lane], acc);
    dsum += we;
  }
  float v = acc / dsum;
  v += __shfl_xor(v, 16);
  v += __shfl_xor(v, 32);
  if (lane < 16) a.out[sel][(size_t)n * C2 + lane] = v * 0.25f + a.bias[sel][lane];
}

// ---------------------------------------------------------------------------
// fused small GEMMs + layer-2 logits — split-bf16 MFMA.
// ---------------------------------------------------------------------------
struct GsA {
  const u16* x1h; const u16* x1l; const u16* x2h; const u16* x2l;
  const u16* Wh; const u16* Wl;
  float* hm1; float* hs1; float* hm2T; float* hs2T;
  const float* AMS; const float* AMD; const float* ASS; const float* ASD;
  float* em1s; float* em1d; float* es1s; float* es1d;
  float* em2s; float* em2d; float* es2s; float* es2d;
};
__global__ __launch_bounds__(256) void gemm_small_fused(GsA a){
  __shared__ u16 sAh[32*64], sAl[32*64], sBh[128*64], sBl[128*64];  // 40 KB
  int t = threadIdx.x, lane = t & 63;
  int wv = __builtin_amdgcn_readfirstlane(t >> 6);
  int src = blockIdx.y;
  int bm = blockIdx.x * 32;
  const u16* xh = src ? a.x2h : a.x1h;
  const u16* xl = src ? a.x2l : a.x1l;
  f32x4 acc[2][2] = {};
  int sarow = t >> 3, sac = (t & 7) ^ (sarow & 7);
  const char* gAh = (const char*)(xh + (size_t)(bm + sarow) * 512) + sac * 16;
  const char* gAl = (const char*)(xl + (size_t)(bm + sarow) * 512) + sac * 16;
  char* lAh = (char*)sAh + t * 16;
  char* lAl = (char*)sAl + t * 16;
  const char* gBh[4]; const char* gBl[4];
  #pragma unroll
  for (int q = 0; q < 4; ++q){
    int id = q * 256 + t;
    int br = id >> 3, bc = (id & 7) ^ (br & 7);
    gBh[q] = (const char*)(a.Wh + (size_t)br * 512) + bc * 16;
    gBl[q] = (const char*)(a.Wl + (size_t)br * 512) + bc * 16;
  }
  int r16 = lane & 15, kq = lane >> 4;
  int aoff[2][2], boff[2][2];
  #pragma unroll
  for (int m = 0; m < 2; ++m)
    #pragma unroll
    for (int ks = 0; ks < 2; ++ks){
      int arow = m * 16 + r16;
      int cc = ks * 4 + kq;
      aoff[m][ks] = arow * 128 + ((cc ^ (arow & 7)) * 16);
    }
  #pragma unroll
  for (int n = 0; n < 2; ++n)
    #pragma unroll
    for (int ks = 0; ks < 2; ++ks){
      int brow = wv * 32 + n * 16 + r16;
      int cc = ks * 4 + kq;
      boff[n][ks] = brow * 128 + ((cc ^ (brow & 7)) * 16);
    }
  for (int kb = 0; kb < 1024; kb += 128){
    glds16(gAh + kb, lAh);
    glds16(gAl + kb, lAl);
    #pragma unroll
    for (int q = 0; q < 4; ++q){
      glds16(gBh[q] + kb, (char*)sBh + (q * 256 + t) * 16);
      glds16(gBl[q] + kb, (char*)sBl + (q * 256 + t) * 16);
    }
    __syncthreads();
    #pragma unroll
    for (int ks = 0; ks < 2; ++ks){
      short8 ah[2], al[2], bh[2], bl[2];
      #pragma unroll
      for (int m = 0; m < 2; ++m){
        ah[m] = *(const short8*)((const char*)sAh + aoff[m][ks]);
        al[m] = *(const short8*)((const char*)sAl + aoff[m][ks]);
      }
      #pragma unroll
      for (int n = 0; n < 2; ++n){
        bh[n] = *(const short8*)((const char*)sBh + boff[n][ks]);
        bl[n] = *(const short8*)((const char*)sBl + boff[n][ks]);
      }
      #pragma unroll
      for (int m = 0; m < 2; ++m)
        #pragma unroll
        for (int n = 0; n < 2; ++n){
          acc[m][n] = __builtin_amdgcn_mfma_f32_16x16x32_bf16(ah[m], bh[n], acc[m][n], 0, 0, 0);
          acc[m][n] = __builtin_amdgcn_mfma_f32_16x16x32_bf16(ah[m], bl[n], acc[m][n], 0, 0, 0);
          acc[m][n] = __builtin_amdgcn_mfma_f32_16x16x32_bf16(al[m], bh[n], acc[m][n], 0, 0, 0);
        }
    }
    __syncthreads();
  }
  #pragma unroll
  for (int m = 0; m < 2; ++m){
    #pragma unroll
    for (int n = 0; n < 2; ++n){
      int colB = wv * 32 + n * 16;
      int half = colB >> 6;
      int colh = (colB & 63) + r16;
      int hh = (colB & 63) >> 4;
      int row0 = bm + m * 16 + kq * 4;
      if (src == 0){
        float* o = (half ? a.hs1 : a.hm1) + (size_t)row0 * 64 + colh;
        #pragma unroll
        for (int r = 0; r < 4; ++r) o[(size_t)r * 64] = acc[m][n][r];
      } else {
        float* oT = (half ? a.hs2T : a.hm2T) + (size_t)colh * NN + row0;
        *(float4*)oT = make_float4(acc[m][n][0], acc[m][n][1], acc[m][n][2], acc[m][n][3]);
      }
      const float* AS = half ? a.ASS : a.AMS;
      const float* AD = half ? a.ASD : a.AMD;
      float av = AS[colh], dv = AD[colh];
      float* esP = src ? (half ? a.es2s : a.em2s) : (half ? a.es1s : a.em1s);
      float* edP = src ? (half ? a.es2d : a.em2d) : (half ? a.es1d : a.em1d);
      #pragma unroll
      for (int r = 0; r < 4; ++r){
        float vs = acc[m][n][r] * av;
        float vd = acc[m][n][r] * dv;
        #pragma unroll
        for (int msk = 1; msk < 16; msk <<= 1){
          vs += __shfl_xor(vs, msk);
          vd += __shfl_xor(vd, msk);
        }
        if (r16 == 0){
          int rw = row0 + r;
          esP[rw * HH + hh] = vs;
          edP[rw * HH + hh] = vd;
        }
      }
    }
  }
}

// ---------------------------------------------------------------------------
// rank-based sort
// ---------------------------------------------------------------------------
struct RkA { const float* in[2]; float* us[2]; int* pm[2]; };
__global__ __launch_bounds__(1024) void rank_kernel(RkA a){
  int sid = blockIdx.y;
  int sel = sid >> 2, h = sid & 3;
  const float* evals = a.in[sel];
  __shared__ u64 K[NN];
  __shared__ int red[1024];
  int t = threadIdx.x;
  for (int i = t; i < NN; i += 1024){
    unsigned x = __float_as_uint(evals[i*HH + h]);
    x = (x & 0x80000000u) ? ~x : (x | 0x80000000u);
    K[i] = ((u64)x << 32) | (unsigned)i;
  }
  __syncthreads();
  int jl = t & 63, sp = t >> 6;
  int j = blockIdx.x * 64 + jl;
  u64 myk = K[j];
  int cnt = 0;
  int k0 = sp * 256;
  #pragma unroll 8
  for (int i = 0; i < 256; ++i)
    cnt += (K[k0 + i] < myk) ? 1 : 0;
  red[t] = cnt;
  __syncthreads();
  if (sp == 0){
    int rank = 0;
    #pragma unroll
    for (int s = 0; s < 16; ++s) rank += red[jl + 64*s];
    a.us[sel][h*NN + rank] = evals[j*HH + h];
    a.pm[sel][h*NN + rank] = j;
  }
}

// ---------------------------------------------------------------------------
// prefix sums over sorted sources, gather from TRANSPOSED feature array
// ---------------------------------------------------------------------------
struct PfxA { const float* T[2]; const int* pm[2]; const float* us[2];
              float* P1[2]; float* P2[2]; };
__global__ __launch_bounds__(512) void prefix_kernel(PfxA a, int C){
  int sel = blockIdx.y;
  int Cp = C + 1;
  int h = blockIdx.x / Cp, c = blockIdx.x % Cp;
  const float* Tsrc = a.T[sel];
  const int*   pm   = a.pm[sel] + h * NN;
  const float* us   = a.us[sel] + h * NN;
  float* P1 = a.P1[sel];
  float* P2 = a.P2[sel];
  const float* row = Tsrc + (size_t)(h * C + c) * NN;
  __shared__ float L1[NN], L2[NN];
  __shared__ float T1[8], T2[8], O1[9], O2[9];
  int t = threadIdx.x, lane = t & 63, w = t >> 6;
  size_t base = (size_t)h * (NN + 1);
  float run1 = 0.f, run2 = 0.f;
  for (int cc = 0; cc < 8; ++cc){
    int k = w * 512 + cc * 64 + lane;
    float u = us[k];
    float v = 1.0f;
    if (c < C){ int j = pm[k] & (NN-1); v = row[j]; }
    float t1 = __expf(u) * v;
    float t2 = __expf(0.2f * u) * v;
    float s1 = t1, s2 = t2;
    for (int o = 1; o < 64; o <<= 1){
      float y1 = __shfl_up(s1, o), y2 = __shfl_up(s2, o);
      if (lane >= o){ s1 += y1; s2 += y2; }
    }
    L1[k] = run1 + s1 - t1;
    L2[k] = run2 + s2 - t2;
    run1 += __shfl(s1, 63);
    run2 += __shfl(s2, 63);
  }
  if (lane == 63){ T1[w] = run1; T2[w] = run2; }
  __syncthreads();
  if (t == 0){
    float a1 = 0.f, a2 = 0.f;
    #pragma unroll
    for (int s = 0; s < 8; ++s){ O1[s] = a1; O2[s] = a2; a1 += T1[s]; a2 += T2[s]; }
    O1[8] = a1; O2[8] = a2;
  }
  __syncthreads();
  for (int i = t; i < NN; i += 512){
    P1[(base + i) * Cp + c] = L1[i] + O1[i >> 9];
    P2[(base + i) * Cp + c] = L2[i] + O2[i >> 9];
  }
  if (t == 0){
    P1[(base + NN) * Cp + c] = O1[8];
    P2[(base + NN) * Cp + c] = O2[8];
  }
}

// ---------------------------------------------------------------------------
// dense output via separable leaky-relu softmax
// ---------------------------------------------------------------------------
template<int C, bool MEAN>
__device__ __forceinline__ void dense_body(const float* __restrict__ P1,
    const float* __restrict__ P2, const float* __restrict__ usort,
    const float* __restrict__ ed, const float* __restrict__ bias,
    float* __restrict__ outF, u16* __restrict__ outH, u16* __restrict__ outL, int i){
  constexpr int Cp = C + 1;
  constexpr int NC = HH * C;
  int t = threadIdx.x;
  __shared__ float Ed[HH], E2d[HH], Den[HH];
  __shared__ int   Kh[HH];
  __shared__ float vals[NC > 256 ? 1 : NC];
  if (t < HH){
    float d = ed[i*HH + t];
    float target = -d;
    const float* us = usort + t * NN;
    int lo = 0, hi = NN;
    while (lo < hi){ int mid = (lo + hi) >> 1; if (us[mid] < target) lo = mid + 1; else hi = mid; }
    Kh[t] = lo;
    float e1 = __expf(d), e2 = __expf(0.2f * d);
    Ed[t] = e1; E2d[t] = e2;
    size_t base = (size_t)t * (NN + 1);
    float p1N = P1[(base + NN) * Cp + C];
    float p1k = P1[(base + lo) * Cp + C];
    float p2k = P2[(base + lo) * Cp + C];
    Den[t] = e1 * (p1N - p1k) + e2 * p2k;
  }
  __syncthreads();
  if (!MEAN){
    for (int ch = t; ch < NC; ch += 256){
      int h = ch / C, c = ch % C;
      size_t base = (size_t)h * (NN + 1);
      float p1N = P1[(base + NN)    * Cp + c];
      float p1k = P1[(base + Kh[h]) * Cp + c];
      float p2k = P2[(base + Kh[h]) * Cp + c];
      float num = Ed[h] * (p1N - p1k) + E2d[h] * p2k;
      float val = num / Den[h] + bias[ch];
      u16 hb = f2b(val);
      outH[(size_t)i * NC + ch] = hb;
      outL[(size_t)i * NC + ch] = f2b(val - b2f(hb));
    }
  } else {
    if (t < NC){
      int h = t / C, c = t % C;
      size_t base = (size_t)h * (NN + 1);
      float p1N = P1[(base + NN)    * Cp + c];
      float p1k = P1[(base + Kh[h]) * Cp + c];
      float p2k = P2[(base + Kh[h]) * Cp + c];
      vals[t] = (Ed[h] * (p1N - p1k) + E2d[h] * p2k) / Den[h];
    }
    __syncthreads();
    if (t < C){
      float z = (vals[t] + vals[C + t] + vals[2*C + t] + vals[3*C + t]) * 0.25f + bias[t];
      outF[(size_t)i * C + t] = z;
    }
  }
}

__global__ __launch_bounds__(256) void dense_out1(const float* __restrict__ P1,
    const float* __restrict__ P2, const float* __restrict__ usort,
    const float* __restrict__ ed, const float* __restrict__ bias,
    u16* __restrict__ outH, u16* __restrict__ outL){
  dense_body<C1, false>(P1, P2, usort, ed, bias, nullptr, outH, outL, blockIdx.x);
}

struct Dn2 { const float* P1[2]; const float* P2[2]; const float* us[2];
             const float* ed[2]; const float* bias[2]; float* out[2]; };
__global__ __launch_bounds__(256) void dense_out2(Dn2 a){
  int s = blockIdx.y;
  dense_body<C2, true>(a.P1[s], a.P2[s], a.us[s], a.ed[s], a.bias[s], a.out[s],
                       nullptr, nullptr, blockIdx.x);
}

// ---------------------------------------------------------------------------
extern "C" void kernel_launch(void* const* d_in, const int* in_sizes, int n_in,
                              void* d_out, int out_size, void* d_ws, size_t ws_size,
                              hipStream_t stream){
  const float* X   = (const float*)d_in[0];
  const int*   EI  = (const int*)d_in[1];
  const float* W1  = (const float*)d_in[3];
  const float* A1S = (const float*)d_in[4];
  const float* A1D = (const float*)d_in[5];
  const float* B1  = (const float*)d_in[6];
  const float* WM  = (const float*)d_in[7];
  const float* AMS = (const float*)d_in[8];
  const float* AMD = (const float*)d_in[9];
  const float* BM  = (const float*)d_in[10];
  const float* WS  = (const float*)d_in[11];
  const float* ASS = (const float*)d_in[12];
  const float* ASD = (const float*)d_in[13];
  const float* BS  = (const float*)d_in[14];
  float* OUT = (float*)d_out;
  (void)in_sizes; (void)n_in;

  if (ws_size < (size_t)64 * 1024 * 1024){
    zero_out_kernel<<<dim3((out_size + 255)/256), 256, 0, stream>>>(OUT, out_size);
    return;
  }

  const size_t MB = 1024 * 1024;
  char* w = (char*)d_ws;
  size_t o = 0;
  auto alloc = [&](size_t bytes) -> void* {
    void* p = w + o;
    o += (bytes + 255) & ~(size_t)255;
    return p;
  };
  int*   deg  = (int*)  alloc(NN * 4);
  int*   coff = (int*)  alloc((NN + 1) * 4);
  int*   cur  = (int*)  alloc(NN * 4);
  int*   sidx = (int*)  alloc((size_t)ETOT * 4);
  float* e1s  = (float*)alloc(NN * HH * 4);
  float* e1d  = (float*)alloc(NN * HH * 4);
  float* us1  = (float*)alloc(HH * NN * 4);
  int*   pm1  = (int*)  alloc(HH * NN * 4);
  float* em1s = (float*)alloc(NN * HH * 4);
  float* em1d = (float*)alloc(NN * HH * 4);
  float* es1s = (float*)alloc(NN * HH * 4);
  float* es1d = (float*)alloc(NN * HH * 4);
  float* em2s = (float*)alloc(NN * HH * 4);
  float* em2d = (float*)alloc(NN * HH * 4);
  float* es2s = (float*)alloc(NN * HH * 4);
  float* es2d = (float*)alloc(NN * HH * 4);
  float* us2m = (float*)alloc(HH * NN * 4);
  int*   pm2m = (int*)  alloc(HH * NN * 4);
  float* us2s = (float*)alloc(HH * NN * 4);
  int*   pm2s = (int*)  alloc(HH * NN * 4);
  u16*   Wh2  = (u16*)  alloc(128 * 512 * 2);
  u16*   Wl2  = (u16*)  alloc(128 * 512 * 2);
  char*  BIG  = w + o;
  // --- phase A (GEMM; W staging + split-K partials) ---
  u16*   WhiB = (u16*)(BIG + 0);               // 512*3072*2 = 3.0 MiB
  u16*   WloB = (u16*)(BIG + (size_t)3200*1024);
  float* hp   = (float*)(BIG + 28*MB);          // 4 x 8 MiB partials -> 28..60
  // --- phase B (post-GEMM; x1/x2 stored as split bf16 hi/lo) ---
  u16*   x1h = (u16*)  (BIG + 0*MB);
  u16*   x1l = (u16*)  (BIG + 4*MB);
  u16*   x2h = (u16*)  (BIG + 8*MB);
  u16*   x2l = (u16*)  (BIG + 12*MB);
  float* hT  = (float*)(BIG + 16*MB);
  u16*   h16 = (u16*)  (BIG + 24*MB);
  float* P1a = (float*)(BIG + 28*MB);           // overlays hp (dead after transpose)
  float* P2a = (float*)(BIG + 37*MB);
  // --- phase C (from gemm_small_fused on; overlays hT/h16 region) ---
  float* hm1  = (float*)(BIG + 16*MB);
  float* hs1  = (float*)(BIG + 17*MB);
  float* hm2T = (float*)(BIG + 18*MB);
  float* hs2T = (float*)(BIG + 19*MB);
  float* P1m  = (float*)(BIG + 20*MB);
  float* P2m  = (float*)(BIG + 21*MB + 512*1024);
  float* P1s  = (float*)(BIG + 23*MB);
  float* P2s  = (float*)(BIG + 24*MB + 512*1024);

  const int* srcA = EI;
  const int* dstA = EI + EE;

  // 0. weight conversions
  cvtW1_kernel<<<dim3(48*8), 256, 0, stream>>>(W1, WhiB, WloB);
  cvtW2_kernel<<<dim3(8, 2), 256, 0, stream>>>(WM, WS, Wh2, Wl2);
  // 1. h = X @ W1 (split-K=4 partials)
  gemm_mfma3<<<dim3(512), 256, 0, stream>>>(X, WhiB, WloB, hp);
  // 2. reduce + transpose + bf16 copy + layer-1 logits (fused)
  transpose_h_red<<<dim3(64, 4), 256, 0, stream>>>(hp, hT, h16, A1S, A1D, e1s, e1d);
  // 3. CSR
  zero_kernel<<<dim3(16), 256, 0, stream>>>(deg, NN);
  hist_kernel<<<dim3((ETOT + 255)/256), 256, 0, stream>>>(dstA, deg);
  scan_kernel<<<dim3(1), 1024, 0, stream>>>(deg, coff, cur);
  scatter_kernel<<<dim3((ETOT + 255)/256), 256, 0, stream>>>(srcA, dstA, cur, sidx);
  // 4. sparse layer 1 -> x1 (split bf16)
  sparse1<<<dim3(NN), 256, 0, stream>>>(h16, e1s, e1d, coff, sidx, B1, x1h, x1l);
  // 5. dense layer 1 -> x2 (split bf16)
  {
    RkA ra; ra.in[0] = e1s; ra.in[1] = e1s; ra.us[0] = us1; ra.us[1] = us1;
    ra.pm[0] = pm1; ra.pm[1] = pm1;
    rank_kernel<<<dim3(64, 4), 1024, 0, stream>>>(ra);
    PfxA pa; pa.T[0] = hT; pa.T[1] = hT; pa.pm[0] = pm1; pa.pm[1] = pm1;
    pa.us[0] = us1; pa.us[1] = us1; pa.P1[0] = P1a; pa.P1[1] = P1a;
    pa.P2[0] = P2a; pa.P2[1] = P2a;
    prefix_kernel<<<dim3(HH*(C1+1), 1), 512, 0, stream>>>(pa, C1);
    dense_out1<<<dim3(NN), 256, 0, stream>>>(P1a, P2a, us1, e1d, B1, x2h, x2l);
  }
  // 6. fused projections + layer-2 logits (split-bf16 MFMA)
  {
    GsA ga;
    ga.x1h = x1h; ga.x1l = x1l; ga.x2h = x2h; ga.x2l = x2l;
    ga.Wh = Wh2; ga.Wl = Wl2;
    ga.hm1 = hm1; ga.hs1 = hs1; ga.hm2T = hm2T; ga.hs2T = hs2T;
    ga.AMS = AMS; ga.AMD = AMD; ga.ASS = ASS; ga.ASD = ASD;
    ga.em1s = em1s; ga.em1d = em1d; ga.es1s = es1s; ga.es1d = es1d;
    ga.em2s = em2s; ga.em2d = em2d; ga.es2s = es2s; ga.es2d = es2d;
    gemm_small_fused<<<dim3(NN/32, 2), 256, 0, stream>>>(ga);
  }
  // 7. sparse layer 2 -> z_mean1, z_log_std1
  {
    Sp2 sp;
    sp.h[0] = hm1; sp.h[1] = hs1; sp.es[0] = em1s; sp.es[1] = es1s;
    sp.ed[0] = em1d; sp.ed[1] = es1d; sp.bias[0] = BM; sp.bias[1] = BS;
    sp.out[0] = OUT; sp.out[1] = OUT + (size_t)NN*C2;
    sparse2<<<dim3(NN, 2), 64, 0, stream>>>(sp, coff, sidx);
  }
  // 8. dense layer 2 -> z_mean2, z_log_std2
  {
    RkA ra; ra.in[0] = em2s; ra.in[1] = es2s; ra.us[0] = us2m; ra.us[1] = us2s;
    ra.pm[0] = pm2m; ra.pm[1] = pm2s;
    rank_kernel<<<dim3(64, 8), 1024, 0, stream>>>(ra);
    PfxA pa; pa.T[0] = hm2T; pa.T[1] = hs2T; pa.pm[0] = pm2m; pa.pm[1] = pm2s;
    pa.us[0] = us2m; pa.us[1] = us2s; pa.P1[0] = P1m; pa.P1[1] = P1s;
    pa.P2[0] = P2m; pa.P2[1] = P2s;
    prefix_kernel<<<dim3(HH*(C2+1), 2), 512, 0, stream>>>(pa, C2);
    Dn2 dn;
    dn.P1[0] = P1m; dn.P1[1] = P1s; dn.P2[0] = P2m; dn.P2[1] = P2s;
    dn.us[0] = us2m; dn.us[1] = us2s; dn.ed[0] = em2d; dn.ed[1] = es2d;
    dn.bias[0] = BM; dn.bias[1] = BS;
    dn.out[0] = OUT + (size_t)2*NN*C2; dn.out[1] = OUT + (size_t)3*NN*C2;
    dense_out2<<<dim3(NN, 2), 256, 0, stream>>>(dn);
  }
}